// Round 5
// baseline (1399.492 us; speedup 1.0000x reference)
//
#include <hip/hip_runtime.h>

#define D128 128

typedef __attribute__((ext_vector_type(8))) short bf16x8;
typedef __attribute__((ext_vector_type(4))) float f32x4;
typedef unsigned short u16;
typedef unsigned int u32;

__device__ __forceinline__ u16 f2b(float f) {
  union { float f; u32 u; } x; x.f = f;
  u32 r = x.u + 0x7fffu + ((x.u >> 16) & 1u);
  return (u16)(r >> 16);
}
__device__ __forceinline__ float b2f(short s) {
  union { u32 u; float f; } x; x.u = ((u32)(unsigned short)s) << 16; return x.f;
}

#define GLD16(gp, lp) __builtin_amdgcn_global_load_lds( \
    (const __attribute__((address_space(1))) void*)(gp), \
    (__attribute__((address_space(3))) void*)(lp), 16, 0, 0)

// device-scope grid barrier: release-fence + agent atomic arrive + spin + acquire.
// One counter per sync point (zeroed by a memset before the kernel each call).
__device__ __forceinline__ void gbar(int* c, int nb) {
  __syncthreads();
  if (threadIdx.x == 0) {
    __threadfence();
    __hip_atomic_fetch_add(c, 1, __ATOMIC_RELEASE, __HIP_MEMORY_SCOPE_AGENT);
    while (__hip_atomic_load(c, __ATOMIC_ACQUIRE, __HIP_MEMORY_SCOPE_AGENT) < nb)
      __builtin_amdgcn_s_sleep(2);
  }
  __syncthreads();
  __threadfence();
}

__global__ __launch_bounds__(256, 3) void mega_k(
    const float* __restrict__ xc, const float* __restrict__ xp,
    const float* __restrict__ Wl, const float* __restrict__ blp,
    const float* __restrict__ Wr, const float* __restrict__ Wd,
    const float* __restrict__ bd,
    const int* __restrict__ src, const int* __restrict__ dst,
    const int* __restrict__ rowi, const int* __restrict__ coli,
    u16* __restrict__ B0, u16* __restrict__ B1, u16* __restrict__ B2,
    u16* __restrict__ Wcat,
    int* __restrict__ deg, int* __restrict__ cur, int* __restrict__ offp,
    int* __restrict__ csum, int* __restrict__ cpref, int* __restrict__ adj,
    int* cnts, float* __restrict__ out,
    int NP, int NC, int E, int EL, int nchunk) {
  __shared__ u16 As[128 * 64];
  __shared__ u16 Bs[128 * 64];
  const int tid = threadIdx.x;
  const int NT = NP + NC;
  const int gtid = blockIdx.x * 256 + tid;
  const int gs = gridDim.x * 256;
  const int nb = gridDim.x;
  const int lane = tid & 63;
  const int wid = blockIdx.x * 4 + (tid >> 6);
  const int nw = gridDim.x * 4;

  // ---- P0: cvt x -> B0 (combined node table: protein [0,NP), chem [NP,NT)),
  //          W -> Wcat bf16, zero deg+cur ----
  {
    const int nqx = NT * 32;                    // float4-quads over x
    const int TOT = nqx + 49152 + (2 * NT) / 4; // + W quads + zero int4s
    for (int i = gtid; i < TOT; i += gs) {
      if (i < nqx) {
        const int r = i >> 5, c4 = (i & 31) << 2;
        const float* sp = (r < NP) ? &xp[(size_t)r * D128 + c4]
                                   : &xc[(size_t)(r - NP) * D128 + c4];
        float4 f = *(const float4*)sp;
        uint2 u;
        u.x = (u32)f2b(f.x) | ((u32)f2b(f.y) << 16);
        u.y = (u32)f2b(f.z) | ((u32)f2b(f.w) << 16);
        *(uint2*)&B0[(size_t)i * 4] = u;
      } else if (i < nqx + 49152) {
        const int t = (i - nqx) * 4;
        const int slice = t >> 15, j = (t >> 8) & 127, k = t & 255;
        const float* sw = (k < 128) ? &Wl[(size_t)slice * 16384 + j * 128 + k]
                                    : &Wr[(size_t)slice * 16384 + j * 128 + (k - 128)];
        float4 f = *(const float4*)sw;
        uint2 u;
        u.x = (u32)f2b(f.x) | ((u32)f2b(f.y) << 16);
        u.y = (u32)f2b(f.z) | ((u32)f2b(f.w) << 16);
        *(uint2*)&Wcat[t] = u;
      } else {
        const int z = i - nqx - 49152;
        int4 zv; zv.x = 0; zv.y = 0; zv.z = 0; zv.w = 0;
        ((int4*)deg)[z] = zv;                    // deg and cur are contiguous
      }
    }
  }
  gbar(cnts + 0, nb);

  // ---- P1: degrees (combined node ids) ----
  for (int e = gtid; e < E; e += gs) {
    atomicAdd(&deg[dst[e]], 1);
    atomicAdd(&deg[NP + src[e]], 1);
  }
  gbar(cnts + 1, nb);

  // ---- P2a: per-2048-chunk exclusive scan of deg -> offp, chunk totals -> csum ----
  {
    int* sh = (int*)As;
    for (int c = blockIdx.x; c < nchunk; c += gridDim.x) {
      const int base = c * 2048 + tid * 8;
      int v[8]; int s = 0;
#pragma unroll
      for (int u = 0; u < 8; ++u) { int i = base + u; v[u] = (i < NT) ? deg[i] : 0; s += v[u]; }
      sh[tid] = s; __syncthreads();
#pragma unroll
      for (int o = 1; o < 256; o <<= 1) {
        int t = (tid >= o) ? sh[tid - o] : 0;
        __syncthreads();
        sh[tid] += t;
        __syncthreads();
      }
      int run = sh[tid] - s;
      if (tid == 255) csum[c] = sh[255];
#pragma unroll
      for (int u = 0; u < 8; ++u) { int i = base + u; if (i < NT) offp[i] = run; run += v[u]; }
      __syncthreads();
    }
  }
  gbar(cnts + 2, nb);

  // ---- P2b: exclusive scan of chunk totals (block 0, wave 0; nchunk <= 64) ----
  if (blockIdx.x == 0 && tid < 64) {
    int v = (tid < nchunk) ? csum[tid] : 0;
    int x = v;
#pragma unroll
    for (int o = 1; o < 64; o <<= 1) {
      int t = __shfl_up(x, o, 64);
      if (lane >= o) x += t;
    }
    cpref[tid] = x - v;
  }
  gbar(cnts + 3, nb);

  // ---- P3: fill adjacency with combined ids (off = offp[v] + cpref[v>>11]) ----
  for (int e = gtid; e < E; e += gs) {
    const int s = src[e], d = dst[e];
    const int cn = NP + s;
    int pp = atomicAdd(&cur[d], 1);
    adj[offp[d] + cpref[d >> 11] + pp] = cn;
    int pc = atomicAdd(&cur[cn], 1);
    adj[offp[cn] + cpref[cn >> 11] + pc] = d;
  }
  gbar(cnts + 4, nb);

  // ---- layers: h0=B0; L0: B0->B1; L1: B1->B2; L2: B2->B1 ----
  const int tilesP = (NP + 127) >> 7;
  const int tilesC = (NC + 127) >> 7;
  for (int l = 0; l < 3; ++l) {
    const u16* hcur; u16* hnext;
    if (l == 0)      { hcur = B0; hnext = B1; }
    else if (l == 1) { hcur = B1; hnext = B2; }
    else             { hcur = B2; hnext = B1; }

    // agg: 4 nodes per wave (16-lane groups), 4-deep gather ILP, 16B/lane loads
    {
      const int g = lane >> 4, l16 = lane & 15;
      for (int n0 = wid * 4; n0 < NT; n0 += nw * 4) {
        const int v = n0 + g;
        int s = 0, cnt = 0;
        if (v < NT) { s = offp[v] + cpref[v >> 11]; cnt = deg[v]; }
        float ac[8] = {0.f, 0.f, 0.f, 0.f, 0.f, 0.f, 0.f, 0.f};
        for (int n = 0; n < cnt; n += 16) {
          int batch = cnt - n; if (batch > 16) batch = 16;
          int idx = (l16 < batch) ? adj[s + n + l16] : 0;
          int j = 0;
          for (; j + 4 <= batch; j += 4) {
            const int i0 = __shfl(idx, j, 16);
            const int i1 = __shfl(idx, j + 1, 16);
            const int i2 = __shfl(idx, j + 2, 16);
            const int i3 = __shfl(idx, j + 3, 16);
            bf16x8 r0 = *(const bf16x8*)&hcur[(size_t)i0 * D128 + l16 * 8];
            bf16x8 r1 = *(const bf16x8*)&hcur[(size_t)i1 * D128 + l16 * 8];
            bf16x8 r2 = *(const bf16x8*)&hcur[(size_t)i2 * D128 + l16 * 8];
            bf16x8 r3 = *(const bf16x8*)&hcur[(size_t)i3 * D128 + l16 * 8];
#pragma unroll
            for (int k = 0; k < 8; ++k)
              ac[k] += (b2f(r0[k]) + b2f(r1[k])) + (b2f(r2[k]) + b2f(r3[k]));
          }
          for (; j < batch; ++j) {
            const int i0 = __shfl(idx, j, 16);
            bf16x8 r0 = *(const bf16x8*)&hcur[(size_t)i0 * D128 + l16 * 8];
#pragma unroll
            for (int k = 0; k < 8; ++k) ac[k] += b2f(r0[k]);
          }
        }
        if (v < NT) {
          const float inv = (cnt > 0) ? 1.f / (float)cnt : 0.f;
          uint4 pk;
          pk.x = (u32)f2b(ac[0] * inv) | ((u32)f2b(ac[1] * inv) << 16);
          pk.y = (u32)f2b(ac[2] * inv) | ((u32)f2b(ac[3] * inv) << 16);
          pk.z = (u32)f2b(ac[4] * inv) | ((u32)f2b(ac[5] * inv) << 16);
          pk.w = (u32)f2b(ac[6] * inv) | ((u32)f2b(ac[7] * inv) << 16);
          *(uint4*)&hnext[(size_t)v * D128 + l16 * 8] = pk;
        }
      }
    }
    gbar(cnts + 5 + l * 2, nb);

    // gemm: hnext = relu(concat(hnext, hcur) @ Wcat^T + bias), in-place, grid-stride tiles
    {
      const int w = tid >> 6;
      const int wr = w >> 1, wc = w & 1;
      const int l15 = lane & 15, chi = lane >> 4;
      for (int t = blockIdx.x; t < tilesP + tilesC; t += gridDim.x) {
        const bool isP = t < tilesP;
        const int rbase = isP ? t * 128 : NP + (t - tilesP) * 128;
        const int hi = isP ? NP : NT;
        const u16* W = Wcat + (size_t)l * 65536 + (isP ? 0 : 32768);
        const float* bias = blp + (size_t)l * 256 + (isP ? 0 : 128);

        f32x4 acc[4][4];
#pragma unroll
        for (int m = 0; m < 4; ++m)
#pragma unroll
          for (int n = 0; n < 4; ++n) acc[m][n] = (f32x4){0.f, 0.f, 0.f, 0.f};

        for (int ks = 0; ks < 4; ++ks) {
          const int k0 = ks * 64;
          const u16* Xsrc = (k0 < 128) ? hnext : hcur;
          const int kb = k0 & 127;
          __syncthreads();
#pragma unroll
          for (int q = 0; q < 4; ++q) {
            const int ibase = w * 256 + q * 64;
            const int i = ibase + lane;
            const int r = i >> 3;
            const int cg = (i & 7) ^ (r & 7);   // pre-swizzled source chunk
            int rr = rbase + r; if (rr >= hi) rr = hi - 1;
            GLD16(Xsrc + (size_t)rr * D128 + kb + cg * 8, (char*)As + ibase * 16);
            GLD16(W + (size_t)r * 256 + k0 + cg * 8, (char*)Bs + ibase * 16);
          }
          __syncthreads();
#pragma unroll
          for (int kk = 0; kk < 2; ++kk) {
            bf16x8 a[4], bfr[4];
            const int c = kk * 4 + chi;
#pragma unroll
            for (int m = 0; m < 4; ++m) {
              const int r = wr * 64 + m * 16 + l15;
              a[m] = *(const bf16x8*)((const char*)As + (r * 8 + (c ^ (r & 7))) * 16);
            }
#pragma unroll
            for (int n = 0; n < 4; ++n) {
              const int j = wc * 64 + n * 16 + l15;
              bfr[n] = *(const bf16x8*)((const char*)Bs + (j * 8 + (c ^ (j & 7))) * 16);
            }
#pragma unroll
            for (int m = 0; m < 4; ++m)
#pragma unroll
              for (int n = 0; n < 4; ++n)
                acc[m][n] = __builtin_amdgcn_mfma_f32_16x16x32_bf16(a[m], bfr[n], acc[m][n], 0, 0, 0);
          }
        }
#pragma unroll
        for (int n = 0; n < 4; ++n) {
          const int col = wc * 64 + n * 16 + l15;
          const float bv = bias[col];
#pragma unroll
          for (int m = 0; m < 4; ++m) {
            const int rb2 = rbase + wr * 64 + m * 16 + chi * 4;
#pragma unroll
            for (int q = 0; q < 4; ++q) {
              const int row = rb2 + q;
              if (row < hi) {
                float vv = acc[m][n][q] + bv;
                vv = vv > 0.f ? vv : 0.f;
                hnext[(size_t)row * D128 + col] = f2b(vv);
              }
            }
          }
        }
      }
    }
    gbar(cnts + 6 + l * 2, nb);
  }

  // ---- decoder: h_final = B1; z = [hc[row]||hp[col]].Wd + bd, emit x ----
  {
    const u16* hf = B1;
    for (int e = wid; e < EL; e += nw) {
      const int r = rowi[e], c = coli[e];
      const unsigned ua = *(const unsigned*)&hf[((size_t)(NP + r)) * D128 + lane * 2];
      const unsigned ub = *(const unsigned*)&hf[((size_t)c) * D128 + lane * 2];
      const float ax = __uint_as_float(ua << 16), ay = __uint_as_float(ua & 0xffff0000u);
      const float bx = __uint_as_float(ub << 16), by = __uint_as_float(ub & 0xffff0000u);
      const float2 w0 = *(const float2*)&Wd[lane * 2];
      const float2 w1 = *(const float2*)&Wd[128 + lane * 2];
      float p = ax * w0.x + ay * w0.y + bx * w1.x + by * w1.y;
#pragma unroll
      for (int m = 1; m < 64; m <<= 1) p += __shfl_xor(p, m, 64);
      float* xo = out + EL + (size_t)e * 256;
      float2 A; A.x = ax; A.y = ay;
      float2 B; B.x = bx; B.y = by;
      *(float2*)&xo[lane * 2] = A;
      *(float2*)&xo[128 + lane * 2] = B;
      if (lane == 0) out[e] = p + bd[0];
    }
  }
}

// ---------------- host ----------------

extern "C" void kernel_launch(void* const* d_in, const int* in_sizes, int n_in,
                              void* d_out, int out_size, void* d_ws, size_t ws_size,
                              hipStream_t stream) {
  const float* x_chem = (const float*)d_in[0];
  const float* x_prot = (const float*)d_in[1];
  const float* Wl = (const float*)d_in[2];
  const float* bl = (const float*)d_in[3];
  const float* Wr = (const float*)d_in[4];
  const float* Wd = (const float*)d_in[5];
  const float* bd = (const float*)d_in[6];
  const int* src = (const int*)d_in[7];
  const int* dst = (const int*)d_in[8];
  const int* row = (const int*)d_in[9];
  const int* col = (const int*)d_in[10];

  int NC = in_sizes[0] / D128;
  int NP = in_sizes[1] / D128;
  int E  = in_sizes[7];
  int EL = in_sizes[9];
  int NT = NP + NC;
  int nchunk = (NT + 2047) / 2048;
  float* out = (float*)d_out;

  char* w = (char*)d_ws;
  size_t szT = (size_t)NT * D128 * 2;
  u16* B0 = (u16*)w; w += szT;
  u16* B1 = (u16*)w; w += szT;
  u16* B2 = (u16*)w; w += szT;
  u16* Wcat = (u16*)w; w += (size_t)6 * 128 * 256 * 2;
  int* deg  = (int*)w; w += (size_t)NT * 4;   // deg,cur contiguous (fused zeroing)
  int* cur  = (int*)w; w += (size_t)NT * 4;
  int* offp = (int*)w; w += (size_t)NT * 4;
  int* csum = (int*)w; w += 64 * 4;
  int* cpref= (int*)w; w += 64 * 4;
  int* cnts = (int*)w; w += 64 * 4;
  int* adj  = (int*)w; w += (size_t)2 * E * 4;
  if ((size_t)(w - (char*)d_ws) > ws_size) return;

  hipMemsetAsync(cnts, 0, 64 * 4, stream);

  // co-residency-safe grid: occupancy-derived blocks/CU x CU count
  int occ = 0;
  if (hipOccupancyMaxActiveBlocksPerMultiprocessor(&occ, mega_k, 256, 0) != hipSuccess || occ < 1)
    occ = 1;
  int dev = 0;
  hipGetDevice(&dev);
  int ncu = 0;
  if (hipDeviceGetAttribute(&ncu, hipDeviceAttributeMultiprocessorCount, dev) != hipSuccess || ncu < 1)
    ncu = 256;
  long long grid = (long long)occ * (long long)ncu;
  if (grid > 2048) grid = 2048;

  mega_k<<<(int)grid, 256, 0, stream>>>(x_chem, x_prot, Wl, bl, Wr, Wd, bd,
                                        src, dst, row, col,
                                        B0, B1, B2, Wcat, deg, cur, offp, csum, cpref, adj,
                                        cnts, out, NP, NC, E, EL, nchunk);
}

// Round 6
// 483.492 us; speedup vs baseline: 2.8946x; 2.8946x over previous
//
#include <hip/hip_runtime.h>

#define D128 128

typedef __attribute__((ext_vector_type(8))) short bf16x8;
typedef __attribute__((ext_vector_type(4))) float f32x4;
typedef unsigned short u16;
typedef unsigned int u32;

__device__ __forceinline__ u16 f2b(float f) {
  union { float f; u32 u; } x; x.f = f;
  u32 r = x.u + 0x7fffu + ((x.u >> 16) & 1u);
  return (u16)(r >> 16);
}
__device__ __forceinline__ float b2f(short s) {
  union { u32 u; float f; } x; x.u = ((u32)(unsigned short)s) << 16; return x.f;
}

#define GLD16(gp, lp) __builtin_amdgcn_global_load_lds( \
    (const __attribute__((address_space(1))) void*)(gp), \
    (__attribute__((address_space(3))) void*)(lp), 16, 0, 0)

// ---- P0: cvt x -> B0 (combined: protein [0,NP), chem [NP,NT)), W -> Wcat, zero deg+cur ----
__global__ __launch_bounds__(256) void cvt_all_k(const float* __restrict__ xc, const float* __restrict__ xp,
                                                 const float* __restrict__ Wl, const float* __restrict__ Wr,
                                                 u16* __restrict__ B0, u16* __restrict__ Wcat,
                                                 int* __restrict__ zbase, int NP, int NT) {
  const int nqx = NT * 32;
  const int TOT = nqx + 49152 + (2 * NT) / 4;
  for (int i = blockIdx.x * 256 + threadIdx.x; i < TOT; i += gridDim.x * 256) {
    if (i < nqx) {
      const int r = i >> 5, c4 = (i & 31) << 2;
      const float* sp = (r < NP) ? &xp[(size_t)r * D128 + c4]
                                 : &xc[(size_t)(r - NP) * D128 + c4];
      float4 f = *(const float4*)sp;
      uint2 u;
      u.x = (u32)f2b(f.x) | ((u32)f2b(f.y) << 16);
      u.y = (u32)f2b(f.z) | ((u32)f2b(f.w) << 16);
      *(uint2*)&B0[(size_t)i * 4] = u;
    } else if (i < nqx + 49152) {
      const int t = (i - nqx) * 4;
      const int slice = t >> 15, j = (t >> 8) & 127, k = t & 255;
      const float* sw = (k < 128) ? &Wl[(size_t)slice * 16384 + j * 128 + k]
                                  : &Wr[(size_t)slice * 16384 + j * 128 + (k - 128)];
      float4 f = *(const float4*)sw;
      uint2 u;
      u.x = (u32)f2b(f.x) | ((u32)f2b(f.y) << 16);
      u.y = (u32)f2b(f.z) | ((u32)f2b(f.w) << 16);
      *(uint2*)&Wcat[t] = u;
    } else {
      const int z = i - nqx - 49152;
      int4 zv; zv.x = 0; zv.y = 0; zv.z = 0; zv.w = 0;
      ((int4*)zbase)[z] = zv;     // deg and cur contiguous
    }
  }
}

// ---- P1: degrees ----
__global__ __launch_bounds__(256) void degree_k(const int* __restrict__ src, const int* __restrict__ dst,
                                                int* deg, int NP, int E) {
  int e = blockIdx.x * 256 + threadIdx.x;
  if (e >= E) return;
  atomicAdd(&deg[dst[e]], 1);
  atomicAdd(&deg[NP + src[e]], 1);
}

// ---- P2: full exclusive scan in ONE dispatch ----
// block c: brute-sum deg[0 .. c*2048) (cheap, <=NT ints), then scan own 2048 chunk.
__global__ __launch_bounds__(256) void scan_k(const int* __restrict__ deg, int* __restrict__ offp, int NT) {
  __shared__ int sh[256];
  const int c = blockIdx.x;
  const int tid = threadIdx.x;
  int pre = 0;
  const int lim = c * 2048;
  for (int i = tid; i < lim; i += 256) pre += deg[i];
  sh[tid] = pre; __syncthreads();
#pragma unroll
  for (int o = 128; o > 0; o >>= 1) {
    if (tid < o) sh[tid] += sh[tid + o];
    __syncthreads();
  }
  const int base_pre = sh[0];
  __syncthreads();
  const int base = lim + tid * 8;
  int v[8]; int s = 0;
#pragma unroll
  for (int u = 0; u < 8; ++u) { int i = base + u; v[u] = (i < NT) ? deg[i] : 0; s += v[u]; }
  sh[tid] = s; __syncthreads();
#pragma unroll
  for (int o = 1; o < 256; o <<= 1) {
    int t = (tid >= o) ? sh[tid - o] : 0;
    __syncthreads();
    sh[tid] += t;
    __syncthreads();
  }
  int run = sh[tid] - s + base_pre;
#pragma unroll
  for (int u = 0; u < 8; ++u) { int i = base + u; if (i < NT) offp[i] = run; run += v[u]; }
}

// ---- P3: fill adjacency (combined ids) ----
__global__ __launch_bounds__(256) void fill_k(const int* __restrict__ src, const int* __restrict__ dst,
                                              const int* __restrict__ offp, int* cur, int* adj,
                                              int NP, int E) {
  int e = blockIdx.x * 256 + threadIdx.x;
  if (e >= E) return;
  const int s = src[e], d = dst[e];
  const int cn = NP + s;
  int pp = atomicAdd(&cur[d], 1);  adj[offp[d] + pp] = cn;
  int pc = atomicAdd(&cur[cn], 1); adj[offp[cn] + pc] = d;
}

// ---- agg: 4 nodes/wave (16-lane groups), 16B/lane bf16x8 gathers, 4-deep ILP ----
__global__ __launch_bounds__(256) void agg_k(const u16* __restrict__ hcur, u16* __restrict__ hnext,
                                             const int* __restrict__ adj, const int* __restrict__ offp,
                                             const int* __restrict__ deg, int NT) {
  const int v = blockIdx.x * 16 + (threadIdx.x >> 4);
  if (v >= NT) return;
  const int l16 = threadIdx.x & 15;
  const int s = offp[v], cnt = deg[v];
  float ac[8] = {0.f, 0.f, 0.f, 0.f, 0.f, 0.f, 0.f, 0.f};
  for (int n = 0; n < cnt; n += 16) {
    int batch = cnt - n; if (batch > 16) batch = 16;
    int idx = (l16 < batch) ? adj[s + n + l16] : 0;
    int j = 0;
    for (; j + 4 <= batch; j += 4) {
      const int i0 = __shfl(idx, j, 16);
      const int i1 = __shfl(idx, j + 1, 16);
      const int i2 = __shfl(idx, j + 2, 16);
      const int i3 = __shfl(idx, j + 3, 16);
      bf16x8 r0 = *(const bf16x8*)&hcur[(size_t)i0 * D128 + l16 * 8];
      bf16x8 r1 = *(const bf16x8*)&hcur[(size_t)i1 * D128 + l16 * 8];
      bf16x8 r2 = *(const bf16x8*)&hcur[(size_t)i2 * D128 + l16 * 8];
      bf16x8 r3 = *(const bf16x8*)&hcur[(size_t)i3 * D128 + l16 * 8];
#pragma unroll
      for (int k = 0; k < 8; ++k)
        ac[k] += (b2f(r0[k]) + b2f(r1[k])) + (b2f(r2[k]) + b2f(r3[k]));
    }
    for (; j < batch; ++j) {
      const int i0 = __shfl(idx, j, 16);
      bf16x8 r0 = *(const bf16x8*)&hcur[(size_t)i0 * D128 + l16 * 8];
#pragma unroll
      for (int k = 0; k < 8; ++k) ac[k] += b2f(r0[k]);
    }
  }
  const float inv = (cnt > 0) ? 1.f / (float)cnt : 0.f;
  uint4 pk;
  pk.x = (u32)f2b(ac[0] * inv) | ((u32)f2b(ac[1] * inv) << 16);
  pk.y = (u32)f2b(ac[2] * inv) | ((u32)f2b(ac[3] * inv) << 16);
  pk.z = (u32)f2b(ac[4] * inv) | ((u32)f2b(ac[5] * inv) << 16);
  pk.w = (u32)f2b(ac[6] * inv) | ((u32)f2b(ac[7] * inv) << 16);
  *(uint4*)&hnext[(size_t)v * D128 + l16 * 8] = pk;
}

// ---- gemm: hnext = relu(concat(hnext, hcur) @ Wcat_l^T + bias), in-place ----
__global__ __launch_bounds__(256) void gemm_both_k(u16* __restrict__ hnext, const u16* __restrict__ hcur,
                                                   const u16* __restrict__ Wcat_l, const float* __restrict__ bl_l,
                                                   int NP, int NT, int tilesP) {
  __shared__ u16 As[128 * 64];
  __shared__ u16 Bs[128 * 64];
  const int t = blockIdx.x;
  const bool isP = t < tilesP;
  const int rbase = isP ? t * 128 : NP + (t - tilesP) * 128;
  const int hi = isP ? NP : NT;
  const u16* __restrict__ W = Wcat_l + (isP ? 0 : 32768);
  const float* __restrict__ bias = bl_l + (isP ? 0 : 128);

  const int tid = threadIdx.x;
  const int w = tid >> 6, lane = tid & 63;
  const int wr = w >> 1, wc = w & 1;
  const int l15 = lane & 15, chi = lane >> 4;

  f32x4 acc[4][4];
#pragma unroll
  for (int m = 0; m < 4; ++m)
#pragma unroll
    for (int n = 0; n < 4; ++n) acc[m][n] = (f32x4){0.f, 0.f, 0.f, 0.f};

  for (int ks = 0; ks < 4; ++ks) {
    const int k0 = ks * 64;
    const u16* Xsrc = (k0 < 128) ? hnext : hcur;
    const int kb = k0 & 127;
    if (ks) __syncthreads();
#pragma unroll
    for (int q = 0; q < 4; ++q) {
      const int ibase = w * 256 + q * 64;
      const int i = ibase + lane;
      const int r = i >> 3;
      const int cg = (i & 7) ^ (r & 7);
      int rr = rbase + r; if (rr >= hi) rr = hi - 1;
      GLD16(Xsrc + (size_t)rr * D128 + kb + cg * 8, (char*)As + ibase * 16);
      GLD16(W + (size_t)r * 256 + k0 + cg * 8, (char*)Bs + ibase * 16);
    }
    __syncthreads();
#pragma unroll
    for (int kk = 0; kk < 2; ++kk) {
      bf16x8 a[4], bfr[4];
      const int c = kk * 4 + chi;
#pragma unroll
      for (int m = 0; m < 4; ++m) {
        const int r = wr * 64 + m * 16 + l15;
        a[m] = *(const bf16x8*)((const char*)As + (r * 8 + (c ^ (r & 7))) * 16);
      }
#pragma unroll
      for (int n = 0; n < 4; ++n) {
        const int j = wc * 64 + n * 16 + l15;
        bfr[n] = *(const bf16x8*)((const char*)Bs + (j * 8 + (c ^ (j & 7))) * 16);
      }
#pragma unroll
      for (int m = 0; m < 4; ++m)
#pragma unroll
        for (int n = 0; n < 4; ++n)
          acc[m][n] = __builtin_amdgcn_mfma_f32_16x16x32_bf16(a[m], bfr[n], acc[m][n], 0, 0, 0);
    }
  }
#pragma unroll
  for (int n = 0; n < 4; ++n) {
    const int col = wc * 64 + n * 16 + l15;
    const float bv = bias[col];
#pragma unroll
    for (int m = 0; m < 4; ++m) {
      const int rb2 = rbase + wr * 64 + m * 16 + chi * 4;
#pragma unroll
      for (int q = 0; q < 4; ++q) {
        const int row = rb2 + q;
        if (row < hi) {
          float vv = acc[m][n][q] + bv;
          vv = vv > 0.f ? vv : 0.f;
          hnext[(size_t)row * D128 + col] = f2b(vv);
        }
      }
    }
  }
}

// ---- decoder: one edge per wave, float4 x-writes ----
__global__ __launch_bounds__(256) void decoder_k(const u16* __restrict__ hf,
                                                 const int* __restrict__ rowi, const int* __restrict__ coli,
                                                 const float* __restrict__ Wd, const float* __restrict__ bd,
                                                 float* __restrict__ out, int NP, int EL) {
  const int lane = threadIdx.x & 63;
  const int wid = blockIdx.x * 4 + (threadIdx.x >> 6);
  const int nw = gridDim.x * 4;
  const float4 wv = *(const float4*)&Wd[lane * 4];
  const float bdv = bd[0];
  for (int e = wid; e < EL; e += nw) {
    const int r = rowi[e], c = coli[e];
    const u16* hrow = (lane < 32) ? &hf[(size_t)(NP + r) * D128 + lane * 4]
                                  : &hf[(size_t)c * D128 + (lane * 4 - 128)];
    const ushort4 hb = *(const ushort4*)hrow;
    const float x0 = b2f((short)hb.x), x1 = b2f((short)hb.y);
    const float x2 = b2f((short)hb.z), x3 = b2f((short)hb.w);
    float p = x0 * wv.x + x1 * wv.y + x2 * wv.z + x3 * wv.w;
#pragma unroll
    for (int m = 1; m < 64; m <<= 1) p += __shfl_xor(p, m, 64);
    float4 st; st.x = x0; st.y = x1; st.z = x2; st.w = x3;
    *(float4*)&out[(size_t)EL + (size_t)e * 256 + lane * 4] = st;
    if (lane == 0) out[e] = p + bdv;
  }
}

// ---------------- host ----------------

extern "C" void kernel_launch(void* const* d_in, const int* in_sizes, int n_in,
                              void* d_out, int out_size, void* d_ws, size_t ws_size,
                              hipStream_t stream) {
  const float* x_chem = (const float*)d_in[0];
  const float* x_prot = (const float*)d_in[1];
  const float* Wl = (const float*)d_in[2];
  const float* bl = (const float*)d_in[3];
  const float* Wr = (const float*)d_in[4];
  const float* Wd = (const float*)d_in[5];
  const float* bd = (const float*)d_in[6];
  const int* src = (const int*)d_in[7];
  const int* dst = (const int*)d_in[8];
  const int* row = (const int*)d_in[9];
  const int* col = (const int*)d_in[10];

  int NC = in_sizes[0] / D128;
  int NP = in_sizes[1] / D128;
  int E  = in_sizes[7];
  int EL = in_sizes[9];
  int NT = NP + NC;
  int nchunk = (NT + 2047) / 2048;
  float* out = (float*)d_out;

  char* w = (char*)d_ws;
  size_t szT = (size_t)NT * D128 * 2;
  u16* B0 = (u16*)w; w += szT;
  u16* B1 = (u16*)w; w += szT;
  u16* B2 = (u16*)w; w += szT;
  u16* Wcat = (u16*)w; w += (size_t)6 * 128 * 256 * 2;
  int* deg  = (int*)w; w += (size_t)NT * 4;   // deg,cur contiguous (fused zeroing)
  int* cur  = (int*)w; w += (size_t)NT * 4;
  int* offp = (int*)w; w += (size_t)NT * 4;
  int* adj  = (int*)w; w += (size_t)2 * E * 4;
  if ((size_t)(w - (char*)d_ws) > ws_size) return;

  cvt_all_k<<<2048, 256, 0, stream>>>(x_chem, x_prot, Wl, Wr, B0, Wcat, deg, NP, NT);

  int gE = (E + 255) / 256;
  degree_k<<<gE, 256, 0, stream>>>(src, dst, deg, NP, E);
  scan_k<<<nchunk, 256, 0, stream>>>(deg, offp, NT);
  fill_k<<<gE, 256, 0, stream>>>(src, dst, offp, cur, adj, NP, E);

  const int tilesP = (NP + 127) >> 7;
  const int tilesC = (NC + 127) >> 7;
  u16* bufs[4] = {B0, B1, B2, B1};   // L0: B0->B1, L1: B1->B2, L2: B2->B1
  for (int l = 0; l < 3; ++l) {
    const u16* hcur = bufs[l];
    u16* hnext = bufs[l + 1];
    agg_k<<<(NT + 15) / 16, 256, 0, stream>>>(hcur, hnext, adj, offp, deg, NT);
    gemm_both_k<<<tilesP + tilesC, 256, 0, stream>>>(hnext, hcur,
                                                     Wcat + (size_t)l * 65536,
                                                     bl + (size_t)l * 256,
                                                     NP, NT, tilesP);
  }

  decoder_k<<<2048, 256, 0, stream>>>(B1, row, col, Wd, bd, out, NP, EL);
}